// Round 18
// baseline (240.619 us; speedup 1.0000x reference)
//
#include <hip/hip_runtime.h>

// GCN: h1 = relu(GCNConv(x,W1,b1)); s1 = pool(h1); h2 = relu(GCNConv(h1,W2,b2)); s2 = pool(h2)
// out = [h2 (N*64) | per-graph rows [s1(64) s2(64)] (G*128)]
// r19 (resubmit; prior round hit GPUAcquisitionTimeout):
// r18 (best, 235.3us) + INLINE-16 columns: k_bsort writes each node's
// first 16 (padded) col indices to row16[n] (64B); k_agg loads them in the
// SAME round trip as row_ptr/row_blocks/dinv and issues the first 16 gathers
// immediately. For deg<=16 (~90% of nodes, Poisson 12) this removes the
// dependent col->gather round trip: ~3 RTs -> ~2.1 mean.
// CLOSED ideas: pooling folded into agg (r14/r17), multi-node waves (r16).
//  - kept: gb1 unscaled + agg1 EDGE_DINV scalar dinv[src]; s1 in k_gemm2;
//    dedicated k_pool2 for s2.

#define FDIM 64
#define BSHIFT 7                 // 128 nodes per bucket
#define MAXNB 1024               // max buckets (N <= 131072)
#define EBCAP 2048               // ebuf slots per bucket (mean 1536, 13-sigma safe)
#define COLCAP 3072              // col slots per bucket (cnt + <=896 pad)
#define BCAP 4096                // LDS ints for one bucket's padded col region

__device__ __forceinline__ unsigned short f2bf(float f) {   // RNE
    union { float f; unsigned int u; } a; a.f = f;
    unsigned int u = a.u;
    unsigned int r = u + 0x7fffu + ((u >> 16) & 1u);
    return (unsigned short)(r >> 16);
}
__device__ __forceinline__ float bf2f(unsigned short s) {
    union { unsigned int u; float f; } a; a.u = ((unsigned int)s) << 16;
    return a.f;
}

// ---- D1: gemm1u (bx<gemmB) | bucket edge-scatter — independent ranges ----
__global__ __launch_bounds__(256, 4) void k_pre(
    const int* __restrict__ src, const int* __restrict__ dstp, int E,
    int N, int gemmB,
    const float* __restrict__ x, const float* __restrict__ W1,
    int* __restrict__ bucketFill,
    unsigned short* __restrict__ gb1, unsigned int* __restrict__ ebuf) {
    __shared__ __align__(16) char sm[33792];
    int tid = threadIdx.x;
    int bx = blockIdx.x;
    if (bx < gemmB) {
        // gemm1 unscaled: gb1[n,:] = bf16(x[n,:] @ W1); phantom row N zeroed
        float4* Ws = (float4*)sm;                       // 16384 B
        float (*Xs)[68] = (float(*)[68])(sm + 16384);   // 17408 B
        ushort4* GB4 = (ushort4*)gb1;
        if (bx == 0 && tid < 16) GB4[(size_t)N * 16 + tid] = make_ushort4(0, 0, 0, 0);
        const float4* W4 = (const float4*)W1;
        for (int i = tid; i < 1024; i += 256) Ws[i] = W4[i];
        int rowBase = bx * 64;
        for (int i = tid; i < 1024; i += 256) {
            int r = i >> 4, f4 = i & 15;
            float4 v = make_float4(0.f, 0.f, 0.f, 0.f);
            if (rowBase + r < N) v = ((const float4*)x)[(size_t)(rowBase + r) * 16 + f4];
            *(float4*)&Xs[r][f4 * 4] = v;
        }
        __syncthreads();
        int r0 = (tid >> 4) * 4;
        int c4 = tid & 15;
        float4 acc0 = make_float4(0,0,0,0), acc1 = acc0, acc2 = acc0, acc3 = acc0;
#pragma unroll 16
        for (int k = 0; k < 64; k++) {
            float4 w = Ws[k * 16 + c4];
            float x0 = Xs[r0 + 0][k], x1 = Xs[r0 + 1][k], x2 = Xs[r0 + 2][k], x3 = Xs[r0 + 3][k];
            acc0.x += x0 * w.x; acc0.y += x0 * w.y; acc0.z += x0 * w.z; acc0.w += x0 * w.w;
            acc1.x += x1 * w.x; acc1.y += x1 * w.y; acc1.z += x1 * w.z; acc1.w += x1 * w.w;
            acc2.x += x2 * w.x; acc2.y += x2 * w.y; acc2.z += x2 * w.z; acc2.w += x2 * w.w;
            acc3.x += x3 * w.x; acc3.y += x3 * w.y; acc3.z += x3 * w.z; acc3.w += x3 * w.w;
        }
        float4 a[4] = {acc0, acc1, acc2, acc3};
#pragma unroll
        for (int i = 0; i < 4; i++) {
            int row = rowBase + r0 + i;
            if (row < N) {
                ushort4 pk;
                pk.x = f2bf(a[i].x); pk.y = f2bf(a[i].y);
                pk.z = f2bf(a[i].z); pk.w = f2bf(a[i].w);
                GB4[(size_t)row * 16 + c4] = pk;
            }
        }
        return;
    }
    // edge scatter into fixed-stride bucket regions (no global prefix).
    // packed entry: (dst&127)<<17 | src   (src < 2^17)
    int* hist = (int*)sm;            // [MAXNB]
    int* base = hist + MAXNB;        // [MAXNB]
    for (int i = tid; i < MAXNB; i += 256) hist[i] = 0;
    __syncthreads();
    int e0 = (bx - gemmB) * 4096;
    int s[16], d[16], r[16];
#pragma unroll
    for (int k = 0; k < 16; k++) {
        int e = e0 + k * 256 + tid;
        bool valid = e < E;
        s[k] = valid ? src[e] : 0;
        d[k] = valid ? dstp[e] : 0;
        r[k] = valid ? atomicAdd(&hist[d[k] >> BSHIFT], 1) : 0;
    }
    __syncthreads();
    for (int i = tid; i < MAXNB; i += 256) {
        int c = hist[i];
        base[i] = c ? (i << 11) + atomicAdd(&bucketFill[i], c) : 0;
    }
    __syncthreads();
#pragma unroll
    for (int k = 0; k < 16; k++) {
        int e = e0 + k * 256 + tid;
        if (e < E)
            ebuf[base[d[k] >> BSHIFT] + r[k]] =
                (unsigned int)s[k] | ((unsigned int)(d[k] & 127) << 17);
    }
}

// ---- D2: per-bucket padded-CSR finalize in LDS. Bucket b: ebuf region
// [b*2048, +cnt), col region base b*3072. Also emits row16[n] = first 16
// padded col indices (phantom N fill) for the agg inline-gather prelude. ----
__global__ __launch_bounds__(256) void k_bsort(const unsigned int* __restrict__ ebuf,
                                               const int* __restrict__ bucketFill, int N,
                                               int* __restrict__ row_ptr,
                                               int* __restrict__ row_blocks,
                                               int* __restrict__ col,
                                               int* __restrict__ row16,
                                               float* __restrict__ dinv) {
    __shared__ int cntL[128];
    __shared__ int scanL[128];
    __shared__ int fillL[128];
    __shared__ int colL[BCAP];
    __shared__ int padT;
    int b = blockIdx.x;
    int n0 = b << BSHIFT;
    int nCnt = N - n0; if (nCnt > 128) nCnt = 128;
    int t = threadIdx.x;
    if (b == 0 && t == 0) dinv[N] = 0.f;      // phantom node weight
    int cnt = bucketFill[b]; if (cnt > EBCAP) cnt = EBCAP;
    int lo = b << 11, hi = lo + cnt;
    int outBase = b * COLCAP;
    if (t < 128) { cntL[t] = 0; fillL[t] = 0; }
    __syncthreads();
    for (int e = lo + t; e < hi; e += 256)
        atomicAdd(&cntL[ebuf[e] >> 17], 1);
    __syncthreads();
    int pc = 0;
    if (t < 128) { pc = (cntL[t] + 7) & ~7; scanL[t] = pc; }
    __syncthreads();
    for (int off = 1; off < 128; off <<= 1) {
        int u = (t >= off && t < 128) ? scanL[t - off] : 0;
        __syncthreads();
        if (t < 128) scanL[t] += u;
        __syncthreads();
    }
    if (t == 127) padT = scanL[127];
    if (t < nCnt) {
        int ex = scanL[t] - pc;
        row_ptr[n0 + t] = outBase + ex;
        row_blocks[n0 + t] = pc >> 3;
        dinv[n0 + t] = rsqrtf((float)cntL[t] + 1.0f);
        scanL[t] = ex;
    }
    __syncthreads();
    int padTotal = padT;
    if (padTotal <= BCAP) {
        for (int i = t; i < padTotal; i += 256) colL[i] = N;   // phantom fill
        __syncthreads();
        for (int e = lo + t; e < hi; e += 256) {
            unsigned int pr = ebuf[e];
            int d = pr >> 17;
            int r = scanL[d] + atomicAdd(&fillL[d], 1);
            colL[r] = (int)(pr & 0x1FFFFu);
        }
        __syncthreads();
        for (int i = t; i < padTotal; i += 256) col[outBase + i] = colL[i];
        if (t < nCnt) {
            int ex = scanL[t];
            int pcl = (cntL[t] + 7) & ~7;
            int4 q[4];
            int* qi = (int*)q;
#pragma unroll
            for (int i = 0; i < 16; i++)
                qi[i] = (i < pcl) ? colL[ex + i] : N;
            int4* d16 = (int4*)&row16[(size_t)(n0 + t) * 16];
            d16[0] = q[0]; d16[1] = q[1]; d16[2] = q[2]; d16[3] = q[3];
        }
    } else {                    // fallback (statistically unreachable)
        for (int e = lo + t; e < hi; e += 256) {
            unsigned int pr = ebuf[e];
            int d = pr >> 17;
            int r = scanL[d] + atomicAdd(&fillL[d], 1);
            col[outBase + r] = (int)(pr & 0x1FFFFu);
        }
        __syncthreads();
        if (t < nCnt) {
            int pcl = (cntL[t] + 7) & ~7;
            for (int i = cntL[t]; i < pcl; i++) col[outBase + scanL[t] + i] = N;
        }
        __syncthreads();
        if (t < nCnt) {
            int ex = scanL[t];
            int pcl = (cntL[t] + 7) & ~7;
            int4 q[4];
            int* qi = (int*)q;
#pragma unroll
            for (int i = 0; i < 16; i++)
                qi[i] = (i < pcl) ? col[outBase + ex + i] : N;
            int4* d16 = (int4*)&row16[(size_t)(n0 + t) * 16];
            d16[0] = q[0]; d16[1] = q[1]; d16[2] = q[2]; d16[3] = q[3];
        }
    }
}

// ---- D3/D5: pure gather agg (r15-measured 43us form) + inline-16 prelude.
// One node per wave; lane=feature; padded rows (phantom N = zero row,
// dinv[N]=0); 16 gathers in flight; SGPR indices. First 16 col indices come
// from row16[n] loaded in the SAME round trip as row meta -> first gathers
// issue without waiting on the col array. EDGE_DINV: dinv[src] per edge. ----
template <typename OutT, bool EDGE_DINV>
__global__ __launch_bounds__(256) void k_agg(
    const unsigned short* __restrict__ Gb,
    const int* __restrict__ row_ptr, const int* __restrict__ row_blocks,
    const int* __restrict__ col, const int* __restrict__ row16,
    const float* __restrict__ dinv,
    const float* __restrict__ bias, int N, OutT* __restrict__ Out) {
    int w = threadIdx.x >> 6;
    int c = threadIdx.x & 63;
    int n = blockIdx.x * 4 + w;
    if (n >= N) return;
    int e = row_ptr[n] + 16;
    int nb8 = row_blocks[n];
    float dn = dinv[n];
    const int4* R4 = (const int4*)(row16 + (size_t)n * 16);
    int4 ra = R4[0];
    int4 rb = R4[1];
    int4 rc = R4[2];
    int4 rd = R4[3];
    float self = bf2f(Gb[(size_t)n * FDIM + c]);
    float acc = EDGE_DINV ? self * dn : self;
    if (nb8 > 0) {
        // inline 16 (covers nb8<=2; nb8==1 rows have entries 8..15 = N phantom)
        int s0  = __builtin_amdgcn_readfirstlane(ra.x);
        int s1  = __builtin_amdgcn_readfirstlane(ra.y);
        int s2  = __builtin_amdgcn_readfirstlane(ra.z);
        int s3  = __builtin_amdgcn_readfirstlane(ra.w);
        int s4  = __builtin_amdgcn_readfirstlane(rb.x);
        int s5  = __builtin_amdgcn_readfirstlane(rb.y);
        int s6  = __builtin_amdgcn_readfirstlane(rb.z);
        int s7  = __builtin_amdgcn_readfirstlane(rb.w);
        int s8  = __builtin_amdgcn_readfirstlane(rc.x);
        int s9  = __builtin_amdgcn_readfirstlane(rc.y);
        int s10 = __builtin_amdgcn_readfirstlane(rc.z);
        int s11 = __builtin_amdgcn_readfirstlane(rc.w);
        int s12 = __builtin_amdgcn_readfirstlane(rd.x);
        int s13 = __builtin_amdgcn_readfirstlane(rd.y);
        int s14 = __builtin_amdgcn_readfirstlane(rd.z);
        int s15 = __builtin_amdgcn_readfirstlane(rd.w);
        float a0  = bf2f(Gb[(size_t)s0  * FDIM + c]);
        float a1  = bf2f(Gb[(size_t)s1  * FDIM + c]);
        float a2  = bf2f(Gb[(size_t)s2  * FDIM + c]);
        float a3  = bf2f(Gb[(size_t)s3  * FDIM + c]);
        float a4  = bf2f(Gb[(size_t)s4  * FDIM + c]);
        float a5  = bf2f(Gb[(size_t)s5  * FDIM + c]);
        float a6  = bf2f(Gb[(size_t)s6  * FDIM + c]);
        float a7  = bf2f(Gb[(size_t)s7  * FDIM + c]);
        float a8  = bf2f(Gb[(size_t)s8  * FDIM + c]);
        float a9  = bf2f(Gb[(size_t)s9  * FDIM + c]);
        float a10 = bf2f(Gb[(size_t)s10 * FDIM + c]);
        float a11 = bf2f(Gb[(size_t)s11 * FDIM + c]);
        float a12 = bf2f(Gb[(size_t)s12 * FDIM + c]);
        float a13 = bf2f(Gb[(size_t)s13 * FDIM + c]);
        float a14 = bf2f(Gb[(size_t)s14 * FDIM + c]);
        float a15 = bf2f(Gb[(size_t)s15 * FDIM + c]);
        if constexpr (EDGE_DINV) {
            float d0  = dinv[s0],  d1  = dinv[s1],  d2  = dinv[s2],  d3  = dinv[s3];
            float d4  = dinv[s4],  d5  = dinv[s5],  d6  = dinv[s6],  d7  = dinv[s7];
            float d8  = dinv[s8],  d9  = dinv[s9],  d10 = dinv[s10], d11 = dinv[s11];
            float d12 = dinv[s12], d13 = dinv[s13], d14 = dinv[s14], d15 = dinv[s15];
            acc += (((a0*d0 + a1*d1) + (a2*d2 + a3*d3)) + ((a4*d4 + a5*d5) + (a6*d6 + a7*d7)))
                 + (((a8*d8 + a9*d9) + (a10*d10 + a11*d11)) + ((a12*d12 + a13*d13) + (a14*d14 + a15*d15)));
        } else {
            acc += (((a0 + a1) + (a2 + a3)) + ((a4 + a5) + (a6 + a7)))
                 + (((a8 + a9) + (a10 + a11)) + ((a12 + a13) + (a14 + a15)));
        }
        nb8 -= 2;
        if (nb8 < 0) nb8 = 0;
    }
    for (; nb8 >= 2; nb8 -= 2, e += 16) {
        int4 ca = *(const int4*)(col + e);
        int4 cb = *(const int4*)(col + e + 4);
        int4 cc = *(const int4*)(col + e + 8);
        int4 cd = *(const int4*)(col + e + 12);
        int s0  = __builtin_amdgcn_readfirstlane(ca.x);
        int s1  = __builtin_amdgcn_readfirstlane(ca.y);
        int s2  = __builtin_amdgcn_readfirstlane(ca.z);
        int s3  = __builtin_amdgcn_readfirstlane(ca.w);
        int s4  = __builtin_amdgcn_readfirstlane(cb.x);
        int s5  = __builtin_amdgcn_readfirstlane(cb.y);
        int s6  = __builtin_amdgcn_readfirstlane(cb.z);
        int s7  = __builtin_amdgcn_readfirstlane(cb.w);
        int s8  = __builtin_amdgcn_readfirstlane(cc.x);
        int s9  = __builtin_amdgcn_readfirstlane(cc.y);
        int s10 = __builtin_amdgcn_readfirstlane(cc.z);
        int s11 = __builtin_amdgcn_readfirstlane(cc.w);
        int s12 = __builtin_amdgcn_readfirstlane(cd.x);
        int s13 = __builtin_amdgcn_readfirstlane(cd.y);
        int s14 = __builtin_amdgcn_readfirstlane(cd.z);
        int s15 = __builtin_amdgcn_readfirstlane(cd.w);
        float a0  = bf2f(Gb[(size_t)s0  * FDIM + c]);
        float a1  = bf2f(Gb[(size_t)s1  * FDIM + c]);
        float a2  = bf2f(Gb[(size_t)s2  * FDIM + c]);
        float a3  = bf2f(Gb[(size_t)s3  * FDIM + c]);
        float a4  = bf2f(Gb[(size_t)s4  * FDIM + c]);
        float a5  = bf2f(Gb[(size_t)s5  * FDIM + c]);
        float a6  = bf2f(Gb[(size_t)s6  * FDIM + c]);
        float a7  = bf2f(Gb[(size_t)s7  * FDIM + c]);
        float a8  = bf2f(Gb[(size_t)s8  * FDIM + c]);
        float a9  = bf2f(Gb[(size_t)s9  * FDIM + c]);
        float a10 = bf2f(Gb[(size_t)s10 * FDIM + c]);
        float a11 = bf2f(Gb[(size_t)s11 * FDIM + c]);
        float a12 = bf2f(Gb[(size_t)s12 * FDIM + c]);
        float a13 = bf2f(Gb[(size_t)s13 * FDIM + c]);
        float a14 = bf2f(Gb[(size_t)s14 * FDIM + c]);
        float a15 = bf2f(Gb[(size_t)s15 * FDIM + c]);
        if constexpr (EDGE_DINV) {
            float d0  = dinv[s0],  d1  = dinv[s1],  d2  = dinv[s2],  d3  = dinv[s3];
            float d4  = dinv[s4],  d5  = dinv[s5],  d6  = dinv[s6],  d7  = dinv[s7];
            float d8  = dinv[s8],  d9  = dinv[s9],  d10 = dinv[s10], d11 = dinv[s11];
            float d12 = dinv[s12], d13 = dinv[s13], d14 = dinv[s14], d15 = dinv[s15];
            acc += (((a0*d0 + a1*d1) + (a2*d2 + a3*d3)) + ((a4*d4 + a5*d5) + (a6*d6 + a7*d7)))
                 + (((a8*d8 + a9*d9) + (a10*d10 + a11*d11)) + ((a12*d12 + a13*d13) + (a14*d14 + a15*d15)));
        } else {
            acc += (((a0 + a1) + (a2 + a3)) + ((a4 + a5) + (a6 + a7)))
                 + (((a8 + a9) + (a10 + a11)) + ((a12 + a13) + (a14 + a15)));
        }
    }
    if (nb8) {
        int4 ca = *(const int4*)(col + e);
        int4 cb = *(const int4*)(col + e + 4);
        int s0 = __builtin_amdgcn_readfirstlane(ca.x);
        int s1 = __builtin_amdgcn_readfirstlane(ca.y);
        int s2 = __builtin_amdgcn_readfirstlane(ca.z);
        int s3 = __builtin_amdgcn_readfirstlane(ca.w);
        int s4 = __builtin_amdgcn_readfirstlane(cb.x);
        int s5 = __builtin_amdgcn_readfirstlane(cb.y);
        int s6 = __builtin_amdgcn_readfirstlane(cb.z);
        int s7 = __builtin_amdgcn_readfirstlane(cb.w);
        float a0 = bf2f(Gb[(size_t)s0 * FDIM + c]);
        float a1 = bf2f(Gb[(size_t)s1 * FDIM + c]);
        float a2 = bf2f(Gb[(size_t)s2 * FDIM + c]);
        float a3 = bf2f(Gb[(size_t)s3 * FDIM + c]);
        float a4 = bf2f(Gb[(size_t)s4 * FDIM + c]);
        float a5 = bf2f(Gb[(size_t)s5 * FDIM + c]);
        float a6 = bf2f(Gb[(size_t)s6 * FDIM + c]);
        float a7 = bf2f(Gb[(size_t)s7 * FDIM + c]);
        if constexpr (EDGE_DINV) {
            float d0 = dinv[s0], d1 = dinv[s1], d2 = dinv[s2], d3 = dinv[s3];
            float d4 = dinv[s4], d5 = dinv[s5], d6 = dinv[s6], d7 = dinv[s7];
            acc += ((a0*d0 + a1*d1) + (a2*d2 + a3*d3)) + ((a4*d4 + a5*d5) + (a6*d6 + a7*d7));
        } else {
            acc += ((a0 + a1) + (a2 + a3)) + ((a4 + a5) + (a6 + a7));
        }
    }
    float v = fmaxf(acc * dn + bias[c], 0.f);
    if constexpr (sizeof(OutT) == 2)
        Out[(size_t)n * FDIM + c] = f2bf(v);
    else
        Out[(size_t)n * FDIM + c] = v;
}

// ---- D4: gemm2 scaled, bf16 input: gb2[n,:] = bf16(dinv[n]*(h1b[n,:]@W2)).
// Phantom row N zeroed. s1-pool folded in: column sums of the staged h1b
// tile grouped by batch -> atomicAdd into pool[g*128+c]. ----
__global__ __launch_bounds__(256, 4) void k_gemm2(
    const unsigned short* __restrict__ H1b, const float* __restrict__ W2,
    const float* __restrict__ dinv, const int* __restrict__ batch, int N,
    unsigned short* __restrict__ Gb2, float* __restrict__ pool) {
    __shared__ float4 Ws[64 * 16];
    __shared__ float Xs[64][68];
    __shared__ int bsL[64];
    int tid = threadIdx.x;
    ushort4* GB4 = (ushort4*)Gb2;
    if (blockIdx.x == 0 && tid < 16)
        GB4[(size_t)N * 16 + tid] = make_ushort4(0, 0, 0, 0);
    const float4* W4 = (const float4*)W2;
    for (int i = tid; i < 1024; i += 256) Ws[i] = W4[i];
    int rowBase = blockIdx.x * 64;
    if (tid < 64) {
        int row = rowBase + tid;
        bsL[tid] = (row < N) ? batch[row] : -1;
    }
    const ushort4* H4 = (const ushort4*)H1b;
    for (int i = tid; i < 1024; i += 256) {
        int r = i >> 4, u4 = i & 15;
        float4 v = make_float4(0.f, 0.f, 0.f, 0.f);
        if (rowBase + r < N) {
            ushort4 u = H4[(size_t)(rowBase + r) * 16 + u4];
            v = make_float4(bf2f(u.x), bf2f(u.y), bf2f(u.z), bf2f(u.w));
        }
        *(float4*)&Xs[r][u4 * 4] = v;
    }
    __syncthreads();
    int r0 = (tid >> 4) * 4;
    int c4 = tid & 15;
    float4 acc0 = make_float4(0,0,0,0), acc1 = acc0, acc2 = acc0, acc3 = acc0;
#pragma unroll 16
    for (int k = 0; k < 64; k++) {
        float4 w = Ws[k * 16 + c4];
        float x0 = Xs[r0 + 0][k], x1 = Xs[r0 + 1][k], x2 = Xs[r0 + 2][k], x3 = Xs[r0 + 3][k];
        acc0.x += x0 * w.x; acc0.y += x0 * w.y; acc0.z += x0 * w.z; acc0.w += x0 * w.w;
        acc1.x += x1 * w.x; acc1.y += x1 * w.y; acc1.z += x1 * w.z; acc1.w += x1 * w.w;
        acc2.x += x2 * w.x; acc2.y += x2 * w.y; acc2.z += x2 * w.z; acc2.w += x2 * w.w;
        acc3.x += x3 * w.x; acc3.y += x3 * w.y; acc3.z += x3 * w.z; acc3.w += x3 * w.w;
    }
    float4 a[4] = {acc0, acc1, acc2, acc3};
#pragma unroll
    for (int i = 0; i < 4; i++) {
        int row = rowBase + r0 + i;
        if (row < N) {
            float dn = dinv[row];
            ushort4 pk;
            pk.x = f2bf(a[i].x * dn);
            pk.y = f2bf(a[i].y * dn);
            pk.z = f2bf(a[i].z * dn);
            pk.w = f2bf(a[i].w * dn);
            GB4[(size_t)row * 16 + c4] = pk;
        }
    }
    // s1-pool: each thread owns (16-row segment, feature c); sum Xs column
    // runs grouped by graph and flush with atomics. batch sorted -> usually
    // one flush per thread.
    {
        int cc = tid & 63;
        int seg = tid >> 6;
        float run = 0.f; int gcur = -2;
        for (int rl = 0; rl < 16; rl++) {
            int r = seg * 16 + rl;
            int g = bsL[r];
            if (g < 0) break;                  // sorted: rest of segment invalid
            if (g != gcur) {
                if (gcur >= 0) atomicAdd(&pool[(size_t)gcur * 128 + cc], run);
                run = 0.f; gcur = g;
            }
            run += Xs[r][cc];
        }
        if (gcur >= 0) atomicAdd(&pool[(size_t)gcur * 128 + cc], run);
    }
}

// ---- D6: s2-pool, streaming. Wave owns 64 consecutive h2 rows; lane c =
// feature; 8 row-loads in flight; run-accumulate by wave-uniform batch[r];
// ~1 atomic flush per wave (batch sorted -> rare boundary). ----
__global__ __launch_bounds__(256) void k_pool2(const float* __restrict__ H2,
                                               const int* __restrict__ batch,
                                               int N, float* __restrict__ pool) {
    int w = threadIdx.x >> 6;
    int c = threadIdx.x & 63;
    int r0 = blockIdx.x * 256 + w * 64;
    int rEnd = r0 + 64; if (rEnd > N) rEnd = N;
    float run = 0.f; int gcur = -2;
    int r = r0;
    for (; r + 8 <= rEnd; r += 8) {
        float v0 = H2[(size_t)(r + 0) * FDIM + c];
        float v1 = H2[(size_t)(r + 1) * FDIM + c];
        float v2 = H2[(size_t)(r + 2) * FDIM + c];
        float v3 = H2[(size_t)(r + 3) * FDIM + c];
        float v4 = H2[(size_t)(r + 4) * FDIM + c];
        float v5 = H2[(size_t)(r + 5) * FDIM + c];
        float v6 = H2[(size_t)(r + 6) * FDIM + c];
        float v7 = H2[(size_t)(r + 7) * FDIM + c];
        float vv[8] = {v0, v1, v2, v3, v4, v5, v6, v7};
#pragma unroll
        for (int k = 0; k < 8; k++) {
            int g = __builtin_amdgcn_readfirstlane(batch[r + k]);
            if (g != gcur) {
                if (gcur >= 0) atomicAdd(&pool[(size_t)gcur * 128 + 64 + c], run);
                run = 0.f; gcur = g;
            }
            run += vv[k];
        }
    }
    for (; r < rEnd; r++) {
        int g = __builtin_amdgcn_readfirstlane(batch[r]);
        if (g != gcur) {
            if (gcur >= 0) atomicAdd(&pool[(size_t)gcur * 128 + 64 + c], run);
            run = 0.f; gcur = g;
        }
        run += H2[(size_t)r * FDIM + c];
    }
    if (gcur >= 0) atomicAdd(&pool[(size_t)gcur * 128 + 64 + c], run);
}

static inline size_t align256(size_t x) { return (x + 255) & ~(size_t)255; }

extern "C" void kernel_launch(void* const* d_in, const int* in_sizes, int n_in,
                              void* d_out, int out_size, void* d_ws, size_t ws_size,
                              hipStream_t stream) {
    const float* x     = (const float*)d_in[0];
    const int*   ei    = (const int*)d_in[1];
    const int*   batch = (const int*)d_in[2];
    const float* W1    = (const float*)d_in[3];
    const float* b1    = (const float*)d_in[4];
    const float* W2    = (const float*)d_in[5];
    const float* b2    = (const float*)d_in[6];

    const int N = in_sizes[0] / FDIM;
    const int E = in_sizes[1] / 2;
    const int G = 64;
    const int NB = (N + 127) >> BSHIFT;
    const int* src = ei;
    const int* dst = ei + E;

    char* p = (char*)d_ws;
    int* row_ptr     = (int*)p; p += align256(((size_t)N + 1) * 4);
    int* row_blocks  = (int*)p; p += align256((size_t)N * 4);
    int* col         = (int*)p; p += align256((size_t)NB * COLCAP * 4);
    int* row16       = (int*)p; p += align256((size_t)N * 16 * 4);
    int* bucketFill  = (int*)p; p += align256((size_t)MAXNB * 4);
    float* dinv      = (float*)p; p += align256(((size_t)N + 1) * 4);
    unsigned short* gb1 = (unsigned short*)p; p += align256(((size_t)N + 1) * FDIM * 2);
    unsigned short* gb2 = (unsigned short*)p; p += align256(((size_t)N + 1) * FDIM * 2);
    unsigned short* h1b = (unsigned short*)p; p += align256((size_t)N * FDIM * 2);
    unsigned int* ebuf = (unsigned int*)h1b;  // NB*2048*4 = 6.4MB <= 12.8MB; dead before h1b

    float* out  = (float*)d_out;
    float* h2   = out;
    float* pool = out + (size_t)N * FDIM;

    hipMemsetAsync(bucketFill, 0, (size_t)MAXNB * 4, stream);
    hipMemsetAsync(pool, 0, (size_t)G * 128 * 4, stream);

    int gemmB = (N + 63) / 64;
    int aggB  = (N + 3) / 4;
    int scatB = (E + 4095) / 4096;
    int poolB = (N + 255) / 256;

    k_pre<<<gemmB + scatB, 256, 0, stream>>>(src, dst, E, N, gemmB, x, W1,
                                             bucketFill, gb1, ebuf);
    k_bsort<<<NB, 256, 0, stream>>>(ebuf, bucketFill, N, row_ptr, row_blocks,
                                    col, row16, dinv);
    k_agg<unsigned short, true><<<aggB, 256, 0, stream>>>(
        gb1, row_ptr, row_blocks, col, row16, dinv, b1, N, h1b);
    k_gemm2<<<gemmB, 256, 0, stream>>>(h1b, W2, dinv, batch, N, gb2, pool);
    k_agg<float, false><<<aggB, 256, 0, stream>>>(
        gb2, row_ptr, row_blocks, col, row16, dinv, b2, N, h2);
    k_pool2<<<poolB, 256, 0, stream>>>(h2, batch, N, pool);
}

// Round 19
// 232.190 us; speedup vs baseline: 1.0363x; 1.0363x over previous
//
#include <hip/hip_runtime.h>

// GCN: h1 = relu(GCNConv(x,W1,b1)); s1 = pool(h1); h2 = relu(GCNConv(h1,W2,b2)); s2 = pool(h2)
// out = [h2 (N*64) | per-graph rows [s1(64) s2(64)] (G*128)]
// r20 = r18 (best, 235.3us) + pool-zero folded into k_bsort block 0
// (removes one memset dispatch from the serial chain; safe: bsort finishes
// before gemm2's first pool atomics).
// r19 post-mortem: inline-16 NULL->negative (aggs 42.6->45.2) — agg is
// gather-completion-bound (~2TB/s via cross-XCD L2/L3 on random 128B rows),
// NOT round-trip-bound. CLOSED: inline cols (r19), multi-node waves (r16),
// pooling-in-agg (r14/r17). Aggs stay at the r15/r18 measured structure.
//  - kept: gb1 unscaled + agg1 EDGE_DINV scalar dinv[src]; s1 in k_gemm2;
//    dedicated k_pool2 for s2.

#define FDIM 64
#define BSHIFT 7                 // 128 nodes per bucket
#define MAXNB 1024               // max buckets (N <= 131072)
#define EBCAP 2048               // ebuf slots per bucket (mean 1536, 13-sigma safe)
#define COLCAP 3072              // col slots per bucket (cnt + <=896 pad)
#define BCAP 4096                // LDS ints for one bucket's padded col region

__device__ __forceinline__ unsigned short f2bf(float f) {   // RNE
    union { float f; unsigned int u; } a; a.f = f;
    unsigned int u = a.u;
    unsigned int r = u + 0x7fffu + ((u >> 16) & 1u);
    return (unsigned short)(r >> 16);
}
__device__ __forceinline__ float bf2f(unsigned short s) {
    union { unsigned int u; float f; } a; a.u = ((unsigned int)s) << 16;
    return a.f;
}

// ---- D1: gemm1u (bx<gemmB) | bucket edge-scatter — independent ranges ----
__global__ __launch_bounds__(256, 4) void k_pre(
    const int* __restrict__ src, const int* __restrict__ dstp, int E,
    int N, int gemmB,
    const float* __restrict__ x, const float* __restrict__ W1,
    int* __restrict__ bucketFill,
    unsigned short* __restrict__ gb1, unsigned int* __restrict__ ebuf) {
    __shared__ __align__(16) char sm[33792];
    int tid = threadIdx.x;
    int bx = blockIdx.x;
    if (bx < gemmB) {
        // gemm1 unscaled: gb1[n,:] = bf16(x[n,:] @ W1); phantom row N zeroed
        float4* Ws = (float4*)sm;                       // 16384 B
        float (*Xs)[68] = (float(*)[68])(sm + 16384);   // 17408 B
        ushort4* GB4 = (ushort4*)gb1;
        if (bx == 0 && tid < 16) GB4[(size_t)N * 16 + tid] = make_ushort4(0, 0, 0, 0);
        const float4* W4 = (const float4*)W1;
        for (int i = tid; i < 1024; i += 256) Ws[i] = W4[i];
        int rowBase = bx * 64;
        for (int i = tid; i < 1024; i += 256) {
            int r = i >> 4, f4 = i & 15;
            float4 v = make_float4(0.f, 0.f, 0.f, 0.f);
            if (rowBase + r < N) v = ((const float4*)x)[(size_t)(rowBase + r) * 16 + f4];
            *(float4*)&Xs[r][f4 * 4] = v;
        }
        __syncthreads();
        int r0 = (tid >> 4) * 4;
        int c4 = tid & 15;
        float4 acc0 = make_float4(0,0,0,0), acc1 = acc0, acc2 = acc0, acc3 = acc0;
#pragma unroll 16
        for (int k = 0; k < 64; k++) {
            float4 w = Ws[k * 16 + c4];
            float x0 = Xs[r0 + 0][k], x1 = Xs[r0 + 1][k], x2 = Xs[r0 + 2][k], x3 = Xs[r0 + 3][k];
            acc0.x += x0 * w.x; acc0.y += x0 * w.y; acc0.z += x0 * w.z; acc0.w += x0 * w.w;
            acc1.x += x1 * w.x; acc1.y += x1 * w.y; acc1.z += x1 * w.z; acc1.w += x1 * w.w;
            acc2.x += x2 * w.x; acc2.y += x2 * w.y; acc2.z += x2 * w.z; acc2.w += x2 * w.w;
            acc3.x += x3 * w.x; acc3.y += x3 * w.y; acc3.z += x3 * w.z; acc3.w += x3 * w.w;
        }
        float4 a[4] = {acc0, acc1, acc2, acc3};
#pragma unroll
        for (int i = 0; i < 4; i++) {
            int row = rowBase + r0 + i;
            if (row < N) {
                ushort4 pk;
                pk.x = f2bf(a[i].x); pk.y = f2bf(a[i].y);
                pk.z = f2bf(a[i].z); pk.w = f2bf(a[i].w);
                GB4[(size_t)row * 16 + c4] = pk;
            }
        }
        return;
    }
    // edge scatter into fixed-stride bucket regions (no global prefix).
    // packed entry: (dst&127)<<17 | src   (src < 2^17)
    int* hist = (int*)sm;            // [MAXNB]
    int* base = hist + MAXNB;        // [MAXNB]
    for (int i = tid; i < MAXNB; i += 256) hist[i] = 0;
    __syncthreads();
    int e0 = (bx - gemmB) * 4096;
    int s[16], d[16], r[16];
#pragma unroll
    for (int k = 0; k < 16; k++) {
        int e = e0 + k * 256 + tid;
        bool valid = e < E;
        s[k] = valid ? src[e] : 0;
        d[k] = valid ? dstp[e] : 0;
        r[k] = valid ? atomicAdd(&hist[d[k] >> BSHIFT], 1) : 0;
    }
    __syncthreads();
    for (int i = tid; i < MAXNB; i += 256) {
        int c = hist[i];
        base[i] = c ? (i << 11) + atomicAdd(&bucketFill[i], c) : 0;
    }
    __syncthreads();
#pragma unroll
    for (int k = 0; k < 16; k++) {
        int e = e0 + k * 256 + tid;
        if (e < E)
            ebuf[base[d[k] >> BSHIFT] + r[k]] =
                (unsigned int)s[k] | ((unsigned int)(d[k] & 127) << 17);
    }
}

// ---- D2: per-bucket padded-CSR finalize in LDS. Bucket b: ebuf region
// [b*2048, +cnt), col region base b*3072. Block 0 also zeros the pool
// output region (gemm2/pool2 atomics start only after this kernel). ----
__global__ __launch_bounds__(256) void k_bsort(const unsigned int* __restrict__ ebuf,
                                               const int* __restrict__ bucketFill, int N,
                                               int* __restrict__ row_ptr,
                                               int* __restrict__ row_blocks,
                                               int* __restrict__ col,
                                               float* __restrict__ dinv,
                                               float* __restrict__ pool, int poolLen) {
    __shared__ int cntL[128];
    __shared__ int scanL[128];
    __shared__ int fillL[128];
    __shared__ int colL[BCAP];
    __shared__ int padT;
    int b = blockIdx.x;
    int n0 = b << BSHIFT;
    int nCnt = N - n0; if (nCnt > 128) nCnt = 128;
    int t = threadIdx.x;
    if (b == 0 && t == 0) dinv[N] = 0.f;      // phantom node weight
    if (b == 0) {
        for (int i = t; i < poolLen; i += 256) pool[i] = 0.f;
    }
    int cnt = bucketFill[b]; if (cnt > EBCAP) cnt = EBCAP;
    int lo = b << 11, hi = lo + cnt;
    int outBase = b * COLCAP;
    if (t < 128) { cntL[t] = 0; fillL[t] = 0; }
    __syncthreads();
    for (int e = lo + t; e < hi; e += 256)
        atomicAdd(&cntL[ebuf[e] >> 17], 1);
    __syncthreads();
    int pc = 0;
    if (t < 128) { pc = (cntL[t] + 7) & ~7; scanL[t] = pc; }
    __syncthreads();
    for (int off = 1; off < 128; off <<= 1) {
        int u = (t >= off && t < 128) ? scanL[t - off] : 0;
        __syncthreads();
        if (t < 128) scanL[t] += u;
        __syncthreads();
    }
    if (t == 127) padT = scanL[127];
    if (t < nCnt) {
        int ex = scanL[t] - pc;
        row_ptr[n0 + t] = outBase + ex;
        row_blocks[n0 + t] = pc >> 3;
        dinv[n0 + t] = rsqrtf((float)cntL[t] + 1.0f);
        scanL[t] = ex;
    }
    __syncthreads();
    int padTotal = padT;
    if (padTotal <= BCAP) {
        for (int i = t; i < padTotal; i += 256) colL[i] = N;   // phantom fill
        __syncthreads();
        for (int e = lo + t; e < hi; e += 256) {
            unsigned int pr = ebuf[e];
            int d = pr >> 17;
            int r = scanL[d] + atomicAdd(&fillL[d], 1);
            colL[r] = (int)(pr & 0x1FFFFu);
        }
        __syncthreads();
        for (int i = t; i < padTotal; i += 256) col[outBase + i] = colL[i];
    } else {                    // fallback (statistically unreachable)
        for (int e = lo + t; e < hi; e += 256) {
            unsigned int pr = ebuf[e];
            int d = pr >> 17;
            int r = scanL[d] + atomicAdd(&fillL[d], 1);
            col[outBase + r] = (int)(pr & 0x1FFFFu);
        }
        __syncthreads();
        if (t < nCnt) {
            int pcl = (cntL[t] + 7) & ~7;
            for (int i = cntL[t]; i < pcl; i++) col[outBase + scanL[t] + i] = N;
        }
    }
}

// ---- D3/D5: pure gather agg (r15/r18-measured 42.6us form). One node per
// wave; lane=feature; padded rows (phantom N = zero row, dinv[N]=0); 16
// gathers in flight; SGPR indices. EDGE_DINV: dinv[src] per edge. ----
template <typename OutT, bool EDGE_DINV>
__global__ __launch_bounds__(256) void k_agg(
    const unsigned short* __restrict__ Gb,
    const int* __restrict__ row_ptr, const int* __restrict__ row_blocks,
    const int* __restrict__ col, const float* __restrict__ dinv,
    const float* __restrict__ bias, int N, OutT* __restrict__ Out) {
    int w = threadIdx.x >> 6;
    int c = threadIdx.x & 63;
    int n = blockIdx.x * 4 + w;
    if (n >= N) return;
    int e = row_ptr[n];
    int nb8 = row_blocks[n];
    float dn = dinv[n];
    float self = bf2f(Gb[(size_t)n * FDIM + c]);
    float acc = EDGE_DINV ? self * dn : self;
    for (; nb8 >= 2; nb8 -= 2, e += 16) {
        int4 ca = *(const int4*)(col + e);
        int4 cb = *(const int4*)(col + e + 4);
        int4 cc = *(const int4*)(col + e + 8);
        int4 cd = *(const int4*)(col + e + 12);
        int s0  = __builtin_amdgcn_readfirstlane(ca.x);
        int s1  = __builtin_amdgcn_readfirstlane(ca.y);
        int s2  = __builtin_amdgcn_readfirstlane(ca.z);
        int s3  = __builtin_amdgcn_readfirstlane(ca.w);
        int s4  = __builtin_amdgcn_readfirstlane(cb.x);
        int s5  = __builtin_amdgcn_readfirstlane(cb.y);
        int s6  = __builtin_amdgcn_readfirstlane(cb.z);
        int s7  = __builtin_amdgcn_readfirstlane(cb.w);
        int s8  = __builtin_amdgcn_readfirstlane(cc.x);
        int s9  = __builtin_amdgcn_readfirstlane(cc.y);
        int s10 = __builtin_amdgcn_readfirstlane(cc.z);
        int s11 = __builtin_amdgcn_readfirstlane(cc.w);
        int s12 = __builtin_amdgcn_readfirstlane(cd.x);
        int s13 = __builtin_amdgcn_readfirstlane(cd.y);
        int s14 = __builtin_amdgcn_readfirstlane(cd.z);
        int s15 = __builtin_amdgcn_readfirstlane(cd.w);
        float a0  = bf2f(Gb[(size_t)s0  * FDIM + c]);
        float a1  = bf2f(Gb[(size_t)s1  * FDIM + c]);
        float a2  = bf2f(Gb[(size_t)s2  * FDIM + c]);
        float a3  = bf2f(Gb[(size_t)s3  * FDIM + c]);
        float a4  = bf2f(Gb[(size_t)s4  * FDIM + c]);
        float a5  = bf2f(Gb[(size_t)s5  * FDIM + c]);
        float a6  = bf2f(Gb[(size_t)s6  * FDIM + c]);
        float a7  = bf2f(Gb[(size_t)s7  * FDIM + c]);
        float a8  = bf2f(Gb[(size_t)s8  * FDIM + c]);
        float a9  = bf2f(Gb[(size_t)s9  * FDIM + c]);
        float a10 = bf2f(Gb[(size_t)s10 * FDIM + c]);
        float a11 = bf2f(Gb[(size_t)s11 * FDIM + c]);
        float a12 = bf2f(Gb[(size_t)s12 * FDIM + c]);
        float a13 = bf2f(Gb[(size_t)s13 * FDIM + c]);
        float a14 = bf2f(Gb[(size_t)s14 * FDIM + c]);
        float a15 = bf2f(Gb[(size_t)s15 * FDIM + c]);
        if constexpr (EDGE_DINV) {
            float d0  = dinv[s0],  d1  = dinv[s1],  d2  = dinv[s2],  d3  = dinv[s3];
            float d4  = dinv[s4],  d5  = dinv[s5],  d6  = dinv[s6],  d7  = dinv[s7];
            float d8  = dinv[s8],  d9  = dinv[s9],  d10 = dinv[s10], d11 = dinv[s11];
            float d12 = dinv[s12], d13 = dinv[s13], d14 = dinv[s14], d15 = dinv[s15];
            acc += (((a0*d0 + a1*d1) + (a2*d2 + a3*d3)) + ((a4*d4 + a5*d5) + (a6*d6 + a7*d7)))
                 + (((a8*d8 + a9*d9) + (a10*d10 + a11*d11)) + ((a12*d12 + a13*d13) + (a14*d14 + a15*d15)));
        } else {
            acc += (((a0 + a1) + (a2 + a3)) + ((a4 + a5) + (a6 + a7)))
                 + (((a8 + a9) + (a10 + a11)) + ((a12 + a13) + (a14 + a15)));
        }
    }
    if (nb8) {
        int4 ca = *(const int4*)(col + e);
        int4 cb = *(const int4*)(col + e + 4);
        int s0 = __builtin_amdgcn_readfirstlane(ca.x);
        int s1 = __builtin_amdgcn_readfirstlane(ca.y);
        int s2 = __builtin_amdgcn_readfirstlane(ca.z);
        int s3 = __builtin_amdgcn_readfirstlane(ca.w);
        int s4 = __builtin_amdgcn_readfirstlane(cb.x);
        int s5 = __builtin_amdgcn_readfirstlane(cb.y);
        int s6 = __builtin_amdgcn_readfirstlane(cb.z);
        int s7 = __builtin_amdgcn_readfirstlane(cb.w);
        float a0 = bf2f(Gb[(size_t)s0 * FDIM + c]);
        float a1 = bf2f(Gb[(size_t)s1 * FDIM + c]);
        float a2 = bf2f(Gb[(size_t)s2 * FDIM + c]);
        float a3 = bf2f(Gb[(size_t)s3 * FDIM + c]);
        float a4 = bf2f(Gb[(size_t)s4 * FDIM + c]);
        float a5 = bf2f(Gb[(size_t)s5 * FDIM + c]);
        float a6 = bf2f(Gb[(size_t)s6 * FDIM + c]);
        float a7 = bf2f(Gb[(size_t)s7 * FDIM + c]);
        if constexpr (EDGE_DINV) {
            float d0 = dinv[s0], d1 = dinv[s1], d2 = dinv[s2], d3 = dinv[s3];
            float d4 = dinv[s4], d5 = dinv[s5], d6 = dinv[s6], d7 = dinv[s7];
            acc += ((a0*d0 + a1*d1) + (a2*d2 + a3*d3)) + ((a4*d4 + a5*d5) + (a6*d6 + a7*d7));
        } else {
            acc += ((a0 + a1) + (a2 + a3)) + ((a4 + a5) + (a6 + a7));
        }
    }
    float v = fmaxf(acc * dn + bias[c], 0.f);
    if constexpr (sizeof(OutT) == 2)
        Out[(size_t)n * FDIM + c] = f2bf(v);
    else
        Out[(size_t)n * FDIM + c] = v;
}

// ---- D4: gemm2 scaled, bf16 input: gb2[n,:] = bf16(dinv[n]*(h1b[n,:]@W2)).
// Phantom row N zeroed. s1-pool folded in: column sums of the staged h1b
// tile grouped by batch -> atomicAdd into pool[g*128+c]. ----
__global__ __launch_bounds__(256, 4) void k_gemm2(
    const unsigned short* __restrict__ H1b, const float* __restrict__ W2,
    const float* __restrict__ dinv, const int* __restrict__ batch, int N,
    unsigned short* __restrict__ Gb2, float* __restrict__ pool) {
    __shared__ float4 Ws[64 * 16];
    __shared__ float Xs[64][68];
    __shared__ int bsL[64];
    int tid = threadIdx.x;
    ushort4* GB4 = (ushort4*)Gb2;
    if (blockIdx.x == 0 && tid < 16)
        GB4[(size_t)N * 16 + tid] = make_ushort4(0, 0, 0, 0);
    const float4* W4 = (const float4*)W2;
    for (int i = tid; i < 1024; i += 256) Ws[i] = W4[i];
    int rowBase = blockIdx.x * 64;
    if (tid < 64) {
        int row = rowBase + tid;
        bsL[tid] = (row < N) ? batch[row] : -1;
    }
    const ushort4* H4 = (const ushort4*)H1b;
    for (int i = tid; i < 1024; i += 256) {
        int r = i >> 4, u4 = i & 15;
        float4 v = make_float4(0.f, 0.f, 0.f, 0.f);
        if (rowBase + r < N) {
            ushort4 u = H4[(size_t)(rowBase + r) * 16 + u4];
            v = make_float4(bf2f(u.x), bf2f(u.y), bf2f(u.z), bf2f(u.w));
        }
        *(float4*)&Xs[r][u4 * 4] = v;
    }
    __syncthreads();
    int r0 = (tid >> 4) * 4;
    int c4 = tid & 15;
    float4 acc0 = make_float4(0,0,0,0), acc1 = acc0, acc2 = acc0, acc3 = acc0;
#pragma unroll 16
    for (int k = 0; k < 64; k++) {
        float4 w = Ws[k * 16 + c4];
        float x0 = Xs[r0 + 0][k], x1 = Xs[r0 + 1][k], x2 = Xs[r0 + 2][k], x3 = Xs[r0 + 3][k];
        acc0.x += x0 * w.x; acc0.y += x0 * w.y; acc0.z += x0 * w.z; acc0.w += x0 * w.w;
        acc1.x += x1 * w.x; acc1.y += x1 * w.y; acc1.z += x1 * w.z; acc1.w += x1 * w.w;
        acc2.x += x2 * w.x; acc2.y += x2 * w.y; acc2.z += x2 * w.z; acc2.w += x2 * w.w;
        acc3.x += x3 * w.x; acc3.y += x3 * w.y; acc3.z += x3 * w.z; acc3.w += x3 * w.w;
    }
    float4 a[4] = {acc0, acc1, acc2, acc3};
#pragma unroll
    for (int i = 0; i < 4; i++) {
        int row = rowBase + r0 + i;
        if (row < N) {
            float dn = dinv[row];
            ushort4 pk;
            pk.x = f2bf(a[i].x * dn);
            pk.y = f2bf(a[i].y * dn);
            pk.z = f2bf(a[i].z * dn);
            pk.w = f2bf(a[i].w * dn);
            GB4[(size_t)row * 16 + c4] = pk;
        }
    }
    // s1-pool: each thread owns (16-row segment, feature c); sum Xs column
    // runs grouped by graph and flush with atomics. batch sorted -> usually
    // one flush per thread.
    {
        int cc = tid & 63;
        int seg = tid >> 6;
        float run = 0.f; int gcur = -2;
        for (int rl = 0; rl < 16; rl++) {
            int r = seg * 16 + rl;
            int g = bsL[r];
            if (g < 0) break;                  // sorted: rest of segment invalid
            if (g != gcur) {
                if (gcur >= 0) atomicAdd(&pool[(size_t)gcur * 128 + cc], run);
                run = 0.f; gcur = g;
            }
            run += Xs[r][cc];
        }
        if (gcur >= 0) atomicAdd(&pool[(size_t)gcur * 128 + cc], run);
    }
}

// ---- D6: s2-pool, streaming. Wave owns 64 consecutive h2 rows; lane c =
// feature; 8 row-loads in flight; run-accumulate by wave-uniform batch[r];
// ~1 atomic flush per wave (batch sorted -> rare boundary). ----
__global__ __launch_bounds__(256) void k_pool2(const float* __restrict__ H2,
                                               const int* __restrict__ batch,
                                               int N, float* __restrict__ pool) {
    int w = threadIdx.x >> 6;
    int c = threadIdx.x & 63;
    int r0 = blockIdx.x * 256 + w * 64;
    int rEnd = r0 + 64; if (rEnd > N) rEnd = N;
    float run = 0.f; int gcur = -2;
    int r = r0;
    for (; r + 8 <= rEnd; r += 8) {
        float v0 = H2[(size_t)(r + 0) * FDIM + c];
        float v1 = H2[(size_t)(r + 1) * FDIM + c];
        float v2 = H2[(size_t)(r + 2) * FDIM + c];
        float v3 = H2[(size_t)(r + 3) * FDIM + c];
        float v4 = H2[(size_t)(r + 4) * FDIM + c];
        float v5 = H2[(size_t)(r + 5) * FDIM + c];
        float v6 = H2[(size_t)(r + 6) * FDIM + c];
        float v7 = H2[(size_t)(r + 7) * FDIM + c];
        float vv[8] = {v0, v1, v2, v3, v4, v5, v6, v7};
#pragma unroll
        for (int k = 0; k < 8; k++) {
            int g = __builtin_amdgcn_readfirstlane(batch[r + k]);
            if (g != gcur) {
                if (gcur >= 0) atomicAdd(&pool[(size_t)gcur * 128 + 64 + c], run);
                run = 0.f; gcur = g;
            }
            run += vv[k];
        }
    }
    for (; r < rEnd; r++) {
        int g = __builtin_amdgcn_readfirstlane(batch[r]);
        if (g != gcur) {
            if (gcur >= 0) atomicAdd(&pool[(size_t)gcur * 128 + 64 + c], run);
            run = 0.f; gcur = g;
        }
        run += H2[(size_t)r * FDIM + c];
    }
    if (gcur >= 0) atomicAdd(&pool[(size_t)gcur * 128 + 64 + c], run);
}

static inline size_t align256(size_t x) { return (x + 255) & ~(size_t)255; }

extern "C" void kernel_launch(void* const* d_in, const int* in_sizes, int n_in,
                              void* d_out, int out_size, void* d_ws, size_t ws_size,
                              hipStream_t stream) {
    const float* x     = (const float*)d_in[0];
    const int*   ei    = (const int*)d_in[1];
    const int*   batch = (const int*)d_in[2];
    const float* W1    = (const float*)d_in[3];
    const float* b1    = (const float*)d_in[4];
    const float* W2    = (const float*)d_in[5];
    const float* b2    = (const float*)d_in[6];

    const int N = in_sizes[0] / FDIM;
    const int E = in_sizes[1] / 2;
    const int G = 64;
    const int NB = (N + 127) >> BSHIFT;
    const int* src = ei;
    const int* dst = ei + E;

    char* p = (char*)d_ws;
    int* row_ptr     = (int*)p; p += align256(((size_t)N + 1) * 4);
    int* row_blocks  = (int*)p; p += align256((size_t)N * 4);
    int* col         = (int*)p; p += align256((size_t)NB * COLCAP * 4);
    int* bucketFill  = (int*)p; p += align256((size_t)MAXNB * 4);
    float* dinv      = (float*)p; p += align256(((size_t)N + 1) * 4);
    unsigned short* gb1 = (unsigned short*)p; p += align256(((size_t)N + 1) * FDIM * 2);
    unsigned short* gb2 = (unsigned short*)p; p += align256(((size_t)N + 1) * FDIM * 2);
    unsigned short* h1b = (unsigned short*)p; p += align256((size_t)N * FDIM * 2);
    unsigned int* ebuf = (unsigned int*)h1b;  // NB*2048*4 = 6.4MB <= 12.8MB; dead before h1b

    float* out  = (float*)d_out;
    float* h2   = out;
    float* pool = out + (size_t)N * FDIM;

    hipMemsetAsync(bucketFill, 0, (size_t)MAXNB * 4, stream);

    int gemmB = (N + 63) / 64;
    int aggB  = (N + 3) / 4;
    int scatB = (E + 4095) / 4096;
    int poolB = (N + 255) / 256;

    k_pre<<<gemmB + scatB, 256, 0, stream>>>(src, dst, E, N, gemmB, x, W1,
                                             bucketFill, gb1, ebuf);
    k_bsort<<<NB, 256, 0, stream>>>(ebuf, bucketFill, N, row_ptr, row_blocks,
                                    col, dinv, pool, G * 128);
    k_agg<unsigned short, true><<<aggB, 256, 0, stream>>>(
        gb1, row_ptr, row_blocks, col, dinv, b1, N, h1b);
    k_gemm2<<<gemmB, 256, 0, stream>>>(h1b, W2, dinv, batch, N, gb2, pool);
    k_agg<float, false><<<aggB, 256, 0, stream>>>(
        gb2, row_ptr, row_blocks, col, dinv, b2, N, h2);
    k_pool2<<<poolB, 256, 0, stream>>>(h2, batch, N, pool);
}